// Round 1
// baseline (3150.244 us; speedup 1.0000x reference)
//
#include <hip/hip_runtime.h>

// Problem constants
#define Bv    32
#define Lv    512
#define Hv    512
#define Fv    512
#define Tv    4096
#define Mv    (Bv*Lv)          // 16384 rows
#define NBINSv 256

// d_out layout (floats): out(B,T,H) | pit(B,L) | eng(B,L) | log_dur(B,L) | mel_len(B)
#define OUT_OFF 0
#define PIT_OFF (Bv*(size_t)Tv*Hv)              // 67108864
#define ENG_OFF (PIT_OFF + Mv)
#define DUR_OFF (ENG_OFF + Mv)
#define MEL_OFF (DUR_OFF + Mv)

// ---------------------------------------------------------------------------
// GEMM: C[m, n] = epi( sum_{tap,k} A[row_shift(m,tap), k] * W[tap, k, n] + bias[n] )
// NTAPS=1: plain GEMM (proj). NTAPS=3: K=3 conv folded into K-loop (zero pad).
// EPI=0: relu.  EPI=1: relu + res[m,n].  EPI=2: relu + res + pe[idxp[m]] + ee[idxe[m]]
// Tile: 128x128, BK=16, 256 threads, 8x8 micro-tile, fp32.
// ---------------------------------------------------------------------------
template<int NTAPS, int EPI>
__global__ __launch_bounds__(256) void gemm_kernel(
    const float* __restrict__ A, const float* __restrict__ W,
    const float* __restrict__ bias, float* __restrict__ C,
    const float* __restrict__ res, const float* __restrict__ pe,
    const float* __restrict__ ee, const int* __restrict__ idxp,
    const int* __restrict__ idxe)
{
    constexpr int PADT = (NTAPS - 1) / 2;
    __shared__ float As[16][132];   // transposed A tile: [k][m], +4 pad
    __shared__ float Bs[16][132];   // B tile: [k][n], +4 pad

    const int tid = threadIdx.x;
    const int n0 = blockIdx.x * 128;
    const int m0 = blockIdx.y * 128;
    const int tr = tid >> 4;        // 0..15 -> rows tr*8..tr*8+7
    const int tc = tid & 15;        // 0..15 -> cols tc*8..tc*8+7

    float acc[8][8];
    #pragma unroll
    for (int i = 0; i < 8; ++i)
        #pragma unroll
        for (int j = 0; j < 8; ++j) acc[i][j] = 0.f;

    for (int kt = 0; kt < NTAPS * 32; ++kt) {
        const int tap = kt >> 5;            // kt / 32
        const int h0  = (kt & 31) << 4;     // (kt % 32) * 16

        // ---- load A tile (128 rows x 16 k) transposed into LDS ----
        #pragma unroll
        for (int r = 0; r < 2; ++r) {
            int i  = tid + r * 256;
            int ar = i >> 2;                // 0..127
            int ac = (i & 3) << 2;          // 0,4,8,12
            int m  = m0 + ar;
            int l  = m & (Lv - 1);
            int ls = l + tap - PADT;
            float4 v = make_float4(0.f, 0.f, 0.f, 0.f);
            if (NTAPS == 1 || (unsigned)ls < (unsigned)Lv) {
                v = *(const float4*)(A + (size_t)(m + ls - l) * 512 + h0 + ac);
            }
            As[ac + 0][ar] = v.x; As[ac + 1][ar] = v.y;
            As[ac + 2][ar] = v.z; As[ac + 3][ar] = v.w;
        }
        // ---- load B tile (16 k x 128 n) ----
        #pragma unroll
        for (int r = 0; r < 2; ++r) {
            int i  = tid + r * 256;
            int br = i >> 5;                // 0..15
            int bc = (i & 31) << 2;         // 0..124
            float4 w = *(const float4*)(W + ((size_t)tap * 512 + h0 + br) * 512 + n0 + bc);
            *(float4*)&Bs[br][bc] = w;
        }
        __syncthreads();

        #pragma unroll
        for (int kk = 0; kk < 16; ++kk) {
            float a[8], bb[8];
            *(float4*)&a[0]  = *(const float4*)&As[kk][tr * 8];
            *(float4*)&a[4]  = *(const float4*)&As[kk][tr * 8 + 4];
            *(float4*)&bb[0] = *(const float4*)&Bs[kk][tc * 8];
            *(float4*)&bb[4] = *(const float4*)&Bs[kk][tc * 8 + 4];
            #pragma unroll
            for (int i = 0; i < 8; ++i)
                #pragma unroll
                for (int j = 0; j < 8; ++j)
                    acc[i][j] = fmaf(a[i], bb[j], acc[i][j]);
        }
        __syncthreads();
    }

    // ---- epilogue ----
    #pragma unroll
    for (int i = 0; i < 8; ++i) {
        const int m = m0 + tr * 8 + i;
        const size_t rowoff = (size_t)m * 512;
        int ip = 0, ie = 0;
        if (EPI == 2) { ip = idxp[m]; ie = idxe[m]; }
        #pragma unroll
        for (int jv = 0; jv < 2; ++jv) {
            const int col = n0 + tc * 8 + jv * 4;
            float4 v;
            v.x = fmaxf(acc[i][jv*4+0] + bias[col+0], 0.f);
            v.y = fmaxf(acc[i][jv*4+1] + bias[col+1], 0.f);
            v.z = fmaxf(acc[i][jv*4+2] + bias[col+2], 0.f);
            v.w = fmaxf(acc[i][jv*4+3] + bias[col+3], 0.f);
            if (EPI >= 1) {
                float4 r4 = *(const float4*)(res + rowoff + col);
                v.x += r4.x; v.y += r4.y; v.z += r4.z; v.w += r4.w;
            }
            if (EPI == 2) {
                float4 p4 = *(const float4*)(pe + (size_t)ip * 512 + col);
                float4 e4 = *(const float4*)(ee + (size_t)ie * 512 + col);
                v.x += p4.x + e4.x; v.y += p4.y + e4.y;
                v.z += p4.z + e4.z; v.w += p4.w + e4.w;
            }
            *(float4*)(C + rowoff + col) = v;
        }
    }
}

// ---------------------------------------------------------------------------
// RMSNorm over last dim (512): out = g * h / (sqrt(mean(h^2)) + 1e-8)
// One block (128 threads, float4) per row.
// ---------------------------------------------------------------------------
__global__ __launch_bounds__(128) void rms_kernel(
    const float* __restrict__ h, const float* __restrict__ g, float* __restrict__ o)
{
    const int row = blockIdx.x;
    const int tid = threadIdx.x;
    const float4* hp = (const float4*)(h + (size_t)row * 512);
    float4 v = hp[tid];
    float ss = v.x*v.x + v.y*v.y + v.z*v.z + v.w*v.w;
    #pragma unroll
    for (int off = 32; off; off >>= 1) ss += __shfl_down(ss, off, 64);
    __shared__ float p[2];
    if ((tid & 63) == 0) p[tid >> 6] = ss;
    __syncthreads();
    const float tot = p[0] + p[1];
    const float inv = 1.f / (sqrtf(tot * (1.f / 512.f)) + 1e-8f);
    const float4 gv = ((const float4*)g)[tid];
    float4 ov;
    ov.x = gv.x * v.x * inv; ov.y = gv.y * v.y * inv;
    ov.z = gv.z * v.z * inv; ov.w = gv.w * v.w * inv;
    ((float4*)(o + (size_t)row * 512))[tid] = ov;
}

// ---------------------------------------------------------------------------
// Linear head: o[row] = mask ? 0 : dot(h[row,:], wl) + bl.  4 waves/block, wave/row.
// ---------------------------------------------------------------------------
__global__ __launch_bounds__(256) void linear_kernel(
    const float* __restrict__ h, const float* __restrict__ wl,
    const float* __restrict__ bl, const unsigned char* __restrict__ mask,
    float* __restrict__ o)
{
    const int wave = threadIdx.x >> 6, lane = threadIdx.x & 63;
    const int row = blockIdx.x * 4 + wave;
    const float4* hp = (const float4*)(h + (size_t)row * 512);
    const float4* wp = (const float4*)wl;
    float s = 0.f;
    #pragma unroll
    for (int r = 0; r < 2; ++r) {
        int i = lane + r * 64;
        float4 a = hp[i], b = wp[i];
        s += a.x*b.x + a.y*b.y + a.z*b.z + a.w*b.w;
    }
    #pragma unroll
    for (int off = 32; off; off >>= 1) s += __shfl_down(s, off, 64);
    if (lane == 0) o[row] = mask[row] ? 0.f : (s + bl[0]);
}

// ---------------------------------------------------------------------------
// searchsorted(bins, v, 'left') for pitch & energy targets (255 bins in LDS)
// ---------------------------------------------------------------------------
__global__ __launch_bounds__(256) void idx_kernel(
    const float* __restrict__ pt, const float* __restrict__ et,
    const float* __restrict__ pbins, const float* __restrict__ ebins,
    int* __restrict__ idxp, int* __restrict__ idxe)
{
    __shared__ float pb[NBINSv - 1], eb[NBINSv - 1];
    const int tid = threadIdx.x;
    if (tid < NBINSv - 1) { pb[tid] = pbins[tid]; eb[tid] = ebins[tid]; }
    __syncthreads();
    const int m = blockIdx.x * 256 + tid;
    const float pv = pt[m], ev = et[m];
    int lo = 0, hi = NBINSv - 1;
    while (lo < hi) { int mid = (lo + hi) >> 1; if (pb[mid] < pv) lo = mid + 1; else hi = mid; }
    idxp[m] = lo;
    lo = 0; hi = NBINSv - 1;
    while (lo < hi) { int mid = (lo + hi) >> 1; if (eb[mid] < ev) lo = mid + 1; else hi = mid; }
    idxe[m] = lo;
}

// ---------------------------------------------------------------------------
// Per-batch inclusive cumsum of durations (L=512), plus mel_len (int + float out)
// ---------------------------------------------------------------------------
__global__ __launch_bounds__(512) void cumsum_kernel(
    const int* __restrict__ dur, int* __restrict__ cum,
    int* __restrict__ melint, float* __restrict__ melout)
{
    __shared__ int s[Lv];
    const int b = blockIdx.x, tid = threadIdx.x;
    s[tid] = dur[b * Lv + tid];
    __syncthreads();
    for (int off = 1; off < Lv; off <<= 1) {
        int t = (tid >= off) ? s[tid - off] : 0;
        __syncthreads();
        s[tid] += t;
        __syncthreads();
    }
    cum[b * Lv + tid] = s[tid];
    if (tid == Lv - 1) { melint[b] = s[tid]; melout[b] = (float)s[tid]; }
}

// ---------------------------------------------------------------------------
// Length regulate: out[b,t,:] = (t < mel_len[b]) ? xo[b, idx(b,t), :] : 0
// idx = min(count(cum[b,:] <= t), L-1).  One block (128 thr, float4) per (b,t).
// ---------------------------------------------------------------------------
__global__ __launch_bounds__(128) void regulate_kernel(
    const float* __restrict__ xo, const int* __restrict__ cum,
    const int* __restrict__ melint, float* __restrict__ out)
{
    const int bt = blockIdx.x;
    const int b = bt >> 12;          // / Tv
    const int t = bt & (Tv - 1);
    const int* c = cum + b * Lv;
    int lo = 0, hi = Lv;
    while (lo < hi) { int mid = (lo + hi) >> 1; if (c[mid] <= t) lo = mid + 1; else hi = mid; }
    const int idx = min(lo, Lv - 1);
    const bool valid = t < melint[b];
    float4 v = make_float4(0.f, 0.f, 0.f, 0.f);
    if (valid) v = ((const float4*)(xo + ((size_t)b * Lv + idx) * 512))[threadIdx.x];
    ((float4*)(out + (size_t)bt * 512))[threadIdx.x] = v;
}

// ---------------------------------------------------------------------------
extern "C" void kernel_launch(void* const* d_in, const int* in_sizes, int n_in,
                              void* d_out, int out_size, void* d_ws, size_t ws_size,
                              hipStream_t stream)
{
    const float* x    = (const float*)d_in[0];
    const float* emb  = (const float*)d_in[1];
    const unsigned char* mask = (const unsigned char*)d_in[2];
    const int*   durt = (const int*)d_in[3];
    const float* pt   = (const float*)d_in[4];
    const float* et   = (const float*)d_in[5];
    // d_in[6] = max_len (constant 4096)
    const float* dw1 = (const float*)d_in[7],  *db1 = (const float*)d_in[8],
               * dg1 = (const float*)d_in[9],  *dw2 = (const float*)d_in[10],
               * db2 = (const float*)d_in[11], *dg2 = (const float*)d_in[12],
               * dwl = (const float*)d_in[13], *dbl = (const float*)d_in[14];
    const float* pw1 = (const float*)d_in[15], *pb1 = (const float*)d_in[16],
               * pg1 = (const float*)d_in[17], *pw2 = (const float*)d_in[18],
               * pb2 = (const float*)d_in[19], *pg2 = (const float*)d_in[20],
               * pwl = (const float*)d_in[21], *pbl = (const float*)d_in[22];
    const float* ew1 = (const float*)d_in[23], *eb1 = (const float*)d_in[24],
               * eg1 = (const float*)d_in[25], *ew2 = (const float*)d_in[26],
               * eb2 = (const float*)d_in[27], *eg2 = (const float*)d_in[28],
               * ewl = (const float*)d_in[29], *ebl = (const float*)d_in[30];
    const float* ppw1 = (const float*)d_in[31], *ppb1 = (const float*)d_in[32],
               * ppw2 = (const float*)d_in[33], *ppb2 = (const float*)d_in[34];
    const float* epw1 = (const float*)d_in[35], *epb1 = (const float*)d_in[36],
               * epw2 = (const float*)d_in[37], *epb2 = (const float*)d_in[38];
    const float* spw1 = (const float*)d_in[39], *spb1 = (const float*)d_in[40],
               * spw2 = (const float*)d_in[41], *spb2 = (const float*)d_in[42];
    const float* pbins = (const float*)d_in[43];
    const float* ebins = (const float*)d_in[44];
    const float* pemb  = (const float*)d_in[45];
    const float* eemb  = (const float*)d_in[46];

    float* outf = (float*)d_out;

    // Scratch layout.  In ws: cum(int 16384) | melint(int 32) | idxp | idxe | bufB (xin/xo)
    int*   cum    = (int*)d_ws;
    int*   melint = cum + Mv;
    int*   idxp   = melint + 64;            // aligned
    int*   idxe   = idxp + Mv;
    float* bufB   = (float*)d_ws + 65536;   // Mv*512 floats (33.5 MB)
    // In d_out front region (fully overwritten by regulate at the end):
    float* bufA = outf;                      // Mv*512
    float* bufC = outf + (size_t)Mv * 512;   // Mv*512
    float* bufD = outf + (size_t)Mv * 1024;  // Mv*512

    const dim3 ggrid(Fv / 128, Mv / 128);   // (4, 128)

    // indices + cumsum (independent of everything else)
    idx_kernel<<<Mv / 256, 256, 0, stream>>>(pt, et, pbins, ebins, idxp, idxe);
    cumsum_kernel<<<Bv, Lv, 0, stream>>>(durt, cum, melint, outf + MEL_OFF);

    auto vpred = [&](const float* xin, const float* w1, const float* b1, const float* g1,
                     const float* w2, const float* b2, const float* g2,
                     const float* wl, const float* bl, float* pred) {
        gemm_kernel<3, 0><<<ggrid, 256, 0, stream>>>(xin, w1, b1, bufC,
                                                     nullptr, nullptr, nullptr, nullptr, nullptr);
        rms_kernel<<<Mv, 128, 0, stream>>>(bufC, g1, bufD);
        gemm_kernel<3, 0><<<ggrid, 256, 0, stream>>>(bufD, w2, b2, bufC,
                                                     nullptr, nullptr, nullptr, nullptr, nullptr);
        rms_kernel<<<Mv, 128, 0, stream>>>(bufC, g2, bufD);
        linear_kernel<<<Mv / 4, 256, 0, stream>>>(bufD, wl, bl, mask, pred);
    };

    // duration predictor on x
    vpred(x, dw1, db1, dg1, dw2, db2, dg2, dwl, dbl, outf + DUR_OFF);

    // pitch: xin = x + proj(emb; pp)
    gemm_kernel<1, 0><<<ggrid, 256, 0, stream>>>(emb, ppw1, ppb1, bufA,
                                                 nullptr, nullptr, nullptr, nullptr, nullptr);
    gemm_kernel<1, 1><<<ggrid, 256, 0, stream>>>(bufA, ppw2, ppb2, bufB,
                                                 x, nullptr, nullptr, nullptr, nullptr);
    vpred(bufB, pw1, pb1, pg1, pw2, pb2, pg2, pwl, pbl, outf + PIT_OFF);

    // energy: xin = x + proj(emb; ep)
    gemm_kernel<1, 0><<<ggrid, 256, 0, stream>>>(emb, epw1, epb1, bufA,
                                                 nullptr, nullptr, nullptr, nullptr, nullptr);
    gemm_kernel<1, 1><<<ggrid, 256, 0, stream>>>(bufA, epw2, epb2, bufB,
                                                 x, nullptr, nullptr, nullptr, nullptr);
    vpred(bufB, ew1, eb1, eg1, ew2, eb2, eg2, ewl, ebl, outf + ENG_OFF);

    // xo = x + pitch_emb[idxp] + energy_emb[idxe] + proj(emb; sp)   (fused epilogue)
    gemm_kernel<1, 0><<<ggrid, 256, 0, stream>>>(emb, spw1, spb1, bufA,
                                                 nullptr, nullptr, nullptr, nullptr, nullptr);
    gemm_kernel<1, 2><<<ggrid, 256, 0, stream>>>(bufA, spw2, spb2, bufB,
                                                 x, pemb, eemb, idxp, idxe);

    // length regulate -> out (overwrites the bufA/C/D scratch region completely)
    regulate_kernel<<<Bv * Tv, 128, 0, stream>>>(bufB, cum, melint, outf + OUT_OFF);
}

// Round 2
// 916.413 us; speedup vs baseline: 3.4376x; 3.4376x over previous
//
#include <hip/hip_runtime.h>

// Problem constants
#define Bv    32
#define Lv    512
#define Hv    512
#define Fv    512
#define Tv    4096
#define Mv    (Bv*Lv)          // 16384 rows
#define NBINSv 256

// d_out layout (floats): out(B,T,H) | pit(B,L) | eng(B,L) | log_dur(B,L) | mel_len(B)
#define OUT_OFF 0
#define PIT_OFF (Bv*(size_t)Tv*Hv)              // 67108864
#define ENG_OFF (PIT_OFF + Mv)
#define DUR_OFF (ENG_OFF + Mv)
#define MEL_OFF (DUR_OFF + Mv)

typedef unsigned short ushort;
typedef __attribute__((ext_vector_type(8))) short   bf16x8;   // 8 bf16 in 4 VGPRs
typedef __attribute__((ext_vector_type(4))) float   f32x4;
typedef __attribute__((ext_vector_type(8))) unsigned short u16x8;

__device__ __forceinline__ float b2f(ushort u) {
    union { float f; unsigned u; } x; x.u = ((unsigned)u) << 16; return x.f;
}
__device__ __forceinline__ ushort f2b(float f) {
    union { float f; unsigned u; } x; x.f = f;
    unsigned r = x.u + 0x7fffu + ((x.u >> 16) & 1u);   // RNE
    return (ushort)(r >> 16);
}

#define GLL16(g, l) __builtin_amdgcn_global_load_lds( \
    (const __attribute__((address_space(1))) void*)(g), \
    (__attribute__((address_space(3))) void*)(l), 16, 0, 0)

// ---------------------------------------------------------------------------
// bf16 MFMA GEMM.  C[m,n] = epi( sum_kk A[shift(m,tap),k] * Wt[n][kk] + bias[n] )
// A: [M][512] bf16 row-major. Wt: [512][Ktot] bf16 (pre-transposed weights).
// NTAPS=3 folds the conv taps: kk = tap*512 + k, row shift tap-1, zero pad via
// per-lane zero-page redirect (global_load_lds allows per-lane global addr).
// Tile 128x128, BK=32, 256 thr = 4 waves, each wave 64x64 (4x4 MFMA tiles).
// LDS k-chunk XOR swizzle: slot = (chunk + row/2) & 3 -> 2-way conflicts (free).
// EPI: 0 = relu; 1 = relu + res; 2 = relu + res + pe[idxp[m]] + ee[idxe[m]]
// ---------------------------------------------------------------------------
template<int NTAPS, int EPI>
__global__ __launch_bounds__(256) void gemm_bf16_kernel(
    const ushort* __restrict__ A, const ushort* __restrict__ Bt,
    const float* __restrict__ bias, ushort* __restrict__ C,
    const float* __restrict__ res, const float* __restrict__ pe,
    const float* __restrict__ ee, const int* __restrict__ idxp,
    const int* __restrict__ idxe, const ushort* __restrict__ zp)
{
    constexpr int KTOT = NTAPS * 512;
    __shared__ ushort As[128 * 32];
    __shared__ ushort Bs[128 * 32];

    const int tid = threadIdx.x;
    const int n0 = blockIdx.x * 128;
    const int m0 = blockIdx.y * 128;

    // staging indices: thread t covers row (t>>2)+r*64, 16B slot (t&3)
    const int sar = tid >> 2;
    const int sl  = tid & 3;

    // compute indices
    const int lane = tid & 63;
    const int w    = tid >> 6;
    const int wm   = (w & 1) * 64;
    const int wn   = (w >> 1) * 64;
    const int lr   = lane & 15;
    const int q    = lane >> 4;

    f32x4 acc[4][4];
    #pragma unroll
    for (int i = 0; i < 4; ++i)
        #pragma unroll
        for (int j = 0; j < 4; ++j) {
            f32x4 z = {0.f, 0.f, 0.f, 0.f};
            acc[i][j] = z;
        }

    for (int kt = 0; kt < NTAPS * 16; ++kt) {
        const int tap = (NTAPS == 3) ? (kt >> 4) : 0;
        const int kin = (NTAPS == 3) ? ((kt & 15) << 5) : (kt << 5);

        #pragma unroll
        for (int r = 0; r < 2; ++r) {
            const int row = sar + r * 64;
            const int m   = m0 + row;
            const int qg  = (sl - (row >> 1)) & 3;
            // A tile
            const ushort* asrc;
            if (NTAPS == 3) {
                const int l  = m & (Lv - 1);
                const int ls = l + tap - 1;
                asrc = ((unsigned)ls < (unsigned)Lv)
                     ? A + (size_t)(m + tap - 1) * 512 + kin + qg * 8
                     : zp;
            } else {
                asrc = A + (size_t)m * 512 + kin + qg * 8;
            }
            GLL16(asrc, &As[row * 32 + sl * 8]);
            // B tile (Wt rows are n, contiguous kk)
            const ushort* bsrc = Bt + (size_t)(n0 + row) * KTOT + tap * 512 + kin + qg * 8;
            GLL16(bsrc, &Bs[row * 32 + sl * 8]);
        }
        __syncthreads();

        bf16x8 af[4], bf[4];
        #pragma unroll
        for (int i = 0; i < 4; ++i) {
            const int rm = wm + i * 16 + lr;
            af[i] = *(const bf16x8*)&As[rm * 32 + (((q + (rm >> 1)) & 3) << 3)];
            const int rn = wn + i * 16 + lr;
            bf[i] = *(const bf16x8*)&Bs[rn * 32 + (((q + (rn >> 1)) & 3) << 3)];
        }
        #pragma unroll
        for (int i = 0; i < 4; ++i)
            #pragma unroll
            for (int j = 0; j < 4; ++j)
                acc[i][j] = __builtin_amdgcn_mfma_f32_16x16x32_bf16(
                                af[i], bf[j], acc[i][j], 0, 0, 0);
        __syncthreads();
    }

    // epilogue: C/D layout col = lane&15 (n), row = q*4 + reg (m within 16)
    #pragma unroll
    for (int i = 0; i < 4; ++i) {
        #pragma unroll
        for (int r = 0; r < 4; ++r) {
            const int m = m0 + wm + i * 16 + q * 4 + r;
            const size_t ro = (size_t)m * 512;
            int ip = 0, ie = 0;
            if (EPI == 2) { ip = idxp[m]; ie = idxe[m]; }
            #pragma unroll
            for (int j = 0; j < 4; ++j) {
                const int n = n0 + wn + j * 16 + lr;
                float v = acc[i][j][r] + bias[n];
                v = fmaxf(v, 0.f);
                if (EPI >= 1) v += res[ro + n];
                if (EPI == 2) v += pe[(size_t)ip * 512 + n] + ee[(size_t)ie * 512 + n];
                C[ro + n] = f2b(v);
            }
        }
    }
}

// ---------------------------------------------------------------------------
// fp32 -> bf16 convert (x, embedding): 8 elements/thread
// ---------------------------------------------------------------------------
__global__ __launch_bounds__(256) void convert_kernel(
    const float* __restrict__ X, ushort* __restrict__ Xb)
{
    const size_t i = (size_t)blockIdx.x * 256 + threadIdx.x;
    const float4 a = ((const float4*)X)[2 * i];
    const float4 b = ((const float4*)X)[2 * i + 1];
    u16x8 o;
    o[0] = f2b(a.x); o[1] = f2b(a.y); o[2] = f2b(a.z); o[3] = f2b(a.w);
    o[4] = f2b(b.x); o[5] = f2b(b.y); o[6] = f2b(b.z); o[7] = f2b(b.w);
    *(u16x8*)(Xb + i * 8) = o;
}

// ---------------------------------------------------------------------------
// Weight transpose+convert: W[kk][n] fp32 (Ktot x 512) -> Wt[n][kk] bf16
// ---------------------------------------------------------------------------
__global__ __launch_bounds__(256) void transpose_kernel(
    const float* __restrict__ W, ushort* __restrict__ Wt, int Ktot)
{
    __shared__ float t[32][33];
    const int k0 = blockIdx.x * 32, n0 = blockIdx.y * 32;
    const int r = threadIdx.x >> 5, c = threadIdx.x & 31;
    #pragma unroll
    for (int rr = 0; rr < 4; ++rr)
        t[r + rr * 8][c] = W[(size_t)(k0 + r + rr * 8) * 512 + n0 + c];
    __syncthreads();
    #pragma unroll
    for (int rr = 0; rr < 4; ++rr)
        Wt[(size_t)(n0 + r + rr * 8) * Ktot + k0 + c] = f2b(t[c][r + rr * 8]);
}

// ---------------------------------------------------------------------------
// RMSNorm over last dim (512), bf16 in -> bf16 out, fp32 math
// ---------------------------------------------------------------------------
__global__ __launch_bounds__(128) void rms_kernel(
    const ushort* __restrict__ h, const float* __restrict__ g, ushort* __restrict__ o)
{
    const int row = blockIdx.x;
    const int tid = threadIdx.x;
    const ushort4 hv = ((const ushort4*)(h + (size_t)row * 512))[tid];
    const float v0 = b2f(hv.x), v1 = b2f(hv.y), v2 = b2f(hv.z), v3 = b2f(hv.w);
    float ss = v0 * v0 + v1 * v1 + v2 * v2 + v3 * v3;
    #pragma unroll
    for (int off = 32; off; off >>= 1) ss += __shfl_down(ss, off, 64);
    __shared__ float p[2];
    if ((tid & 63) == 0) p[tid >> 6] = ss;
    __syncthreads();
    const float tot = p[0] + p[1];
    const float inv = 1.f / (sqrtf(tot * (1.f / 512.f)) + 1e-8f);
    const float4 gv = ((const float4*)g)[tid];
    ushort4 ov;
    ov.x = f2b(gv.x * v0 * inv); ov.y = f2b(gv.y * v1 * inv);
    ov.z = f2b(gv.z * v2 * inv); ov.w = f2b(gv.w * v3 * inv);
    ((ushort4*)(o + (size_t)row * 512))[tid] = ov;
}

// ---------------------------------------------------------------------------
// Linear head: o[row] = mask ? 0 : dot(h[row,:], wl) + bl.  wave/row, fp32 math.
// ---------------------------------------------------------------------------
__global__ __launch_bounds__(256) void linear_kernel(
    const ushort* __restrict__ h, const float* __restrict__ wl,
    const float* __restrict__ bl, const unsigned char* __restrict__ mask,
    float* __restrict__ o)
{
    const int wave = threadIdx.x >> 6, lane = threadIdx.x & 63;
    const int row = blockIdx.x * 4 + wave;
    const bf16x8 hv = *(const bf16x8*)(h + (size_t)row * 512 + lane * 8);
    float s = 0.f;
    #pragma unroll
    for (int t = 0; t < 8; ++t) s += b2f((ushort)hv[t]) * wl[lane * 8 + t];
    #pragma unroll
    for (int off = 32; off; off >>= 1) s += __shfl_down(s, off, 64);
    if (lane == 0) o[row] = mask[row] ? 0.f : (s + bl[0]);
}

// ---------------------------------------------------------------------------
// searchsorted(bins, v, 'left') for pitch & energy targets
// ---------------------------------------------------------------------------
__global__ __launch_bounds__(256) void idx_kernel(
    const float* __restrict__ pt, const float* __restrict__ et,
    const float* __restrict__ pbins, const float* __restrict__ ebins,
    int* __restrict__ idxp, int* __restrict__ idxe)
{
    __shared__ float pb[NBINSv - 1], eb[NBINSv - 1];
    const int tid = threadIdx.x;
    if (tid < NBINSv - 1) { pb[tid] = pbins[tid]; eb[tid] = ebins[tid]; }
    __syncthreads();
    const int m = blockIdx.x * 256 + tid;
    const float pv = pt[m], ev = et[m];
    int lo = 0, hi = NBINSv - 1;
    while (lo < hi) { int mid = (lo + hi) >> 1; if (pb[mid] < pv) lo = mid + 1; else hi = mid; }
    idxp[m] = lo;
    lo = 0; hi = NBINSv - 1;
    while (lo < hi) { int mid = (lo + hi) >> 1; if (eb[mid] < ev) lo = mid + 1; else hi = mid; }
    idxe[m] = lo;
}

// ---------------------------------------------------------------------------
// Per-batch inclusive cumsum of durations, plus mel_len
// ---------------------------------------------------------------------------
__global__ __launch_bounds__(512) void cumsum_kernel(
    const int* __restrict__ dur, int* __restrict__ cum,
    int* __restrict__ melint, float* __restrict__ melout)
{
    __shared__ int s[Lv];
    const int b = blockIdx.x, tid = threadIdx.x;
    s[tid] = dur[b * Lv + tid];
    __syncthreads();
    for (int off = 1; off < Lv; off <<= 1) {
        int t = (tid >= off) ? s[tid - off] : 0;
        __syncthreads();
        s[tid] += t;
        __syncthreads();
    }
    cum[b * Lv + tid] = s[tid];
    if (tid == Lv - 1) { melint[b] = s[tid]; melout[b] = (float)s[tid]; }
}

// ---------------------------------------------------------------------------
// Length regulate: out[b,t,:] = (t < mel_len[b]) ? xo[b, idx(b,t), :] : 0
// xo is bf16, out fp32.
// ---------------------------------------------------------------------------
__global__ __launch_bounds__(128) void regulate_kernel(
    const ushort* __restrict__ xo, const int* __restrict__ cum,
    const int* __restrict__ melint, float* __restrict__ out)
{
    const int bt = blockIdx.x;
    const int b = bt >> 12;
    const int t = bt & (Tv - 1);
    const int* c = cum + b * Lv;
    int lo = 0, hi = Lv;
    while (lo < hi) { int mid = (lo + hi) >> 1; if (c[mid] <= t) lo = mid + 1; else hi = mid; }
    const int idx = min(lo, Lv - 1);
    float4 v = make_float4(0.f, 0.f, 0.f, 0.f);
    if (t < melint[b]) {
        const ushort4 u = ((const ushort4*)(xo + (size_t)(b * Lv + idx) * 512))[threadIdx.x];
        v.x = b2f(u.x); v.y = b2f(u.y); v.z = b2f(u.z); v.w = b2f(u.w);
    }
    ((float4*)(out + (size_t)bt * 512))[threadIdx.x] = v;
}

// ---------------------------------------------------------------------------
extern "C" void kernel_launch(void* const* d_in, const int* in_sizes, int n_in,
                              void* d_out, int out_size, void* d_ws, size_t ws_size,
                              hipStream_t stream)
{
    const float* x    = (const float*)d_in[0];
    const float* emb  = (const float*)d_in[1];
    const unsigned char* mask = (const unsigned char*)d_in[2];
    const int*   durt = (const int*)d_in[3];
    const float* pt   = (const float*)d_in[4];
    const float* et   = (const float*)d_in[5];
    const float* dw1 = (const float*)d_in[7],  *db1 = (const float*)d_in[8],
               * dg1 = (const float*)d_in[9],  *dw2 = (const float*)d_in[10],
               * db2 = (const float*)d_in[11], *dg2 = (const float*)d_in[12],
               * dwl = (const float*)d_in[13], *dbl = (const float*)d_in[14];
    const float* pw1 = (const float*)d_in[15], *pb1 = (const float*)d_in[16],
               * pg1 = (const float*)d_in[17], *pw2 = (const float*)d_in[18],
               * pb2 = (const float*)d_in[19], *pg2 = (const float*)d_in[20],
               * pwl = (const float*)d_in[21], *pbl = (const float*)d_in[22];
    const float* ew1 = (const float*)d_in[23], *eb1 = (const float*)d_in[24],
               * eg1 = (const float*)d_in[25], *ew2 = (const float*)d_in[26],
               * eb2 = (const float*)d_in[27], *eg2 = (const float*)d_in[28],
               * ewl = (const float*)d_in[29], *ebl = (const float*)d_in[30];
    const float* ppw1 = (const float*)d_in[31], *ppb1 = (const float*)d_in[32],
               * ppw2 = (const float*)d_in[33], *ppb2 = (const float*)d_in[34];
    const float* epw1 = (const float*)d_in[35], *epb1 = (const float*)d_in[36],
               * epw2 = (const float*)d_in[37], *epb2 = (const float*)d_in[38];
    const float* spw1 = (const float*)d_in[39], *spb1 = (const float*)d_in[40],
               * spw2 = (const float*)d_in[41], *spb2 = (const float*)d_in[42];
    const float* pbins = (const float*)d_in[43];
    const float* ebins = (const float*)d_in[44];
    const float* pemb  = (const float*)d_in[45];
    const float* eemb  = (const float*)d_in[46];

    float* outf = (float*)d_out;

    // ---- ws scratch: cum | melint | idxp | idxe | zeropage | xo(bf16) ----
    int*    cum    = (int*)d_ws;
    int*    melint = cum + Mv;
    int*    idxp   = melint + 64;
    int*    idxe   = idxp + Mv;
    ushort* zp     = (ushort*)((float*)d_ws + 49216);   // 64B zero page (16B aligned)
    ushort* xob    = (ushort*)((float*)d_ws + 65536);   // Mv*512 bf16 = 16.8 MB

    // ---- d_out front region scratch (fully overwritten by regulate) ----
    // bf16 buffers, sizes in float-offsets (1 float = 2 bf16)
    ushort* xb   = (ushort*)(outf + 0);                 // x bf16
    ushort* eb   = (ushort*)(outf + 4194304);           // emb bf16
    ushort* bufA = (ushort*)(outf + 8388608);           // proj hidden
    ushort* bufC = (ushort*)(outf + 12582912);          // conv out
    ushort* bufD = (ushort*)(outf + 16777216);          // rms out
    // transposed bf16 weights
    ushort* wt[12];
    {
        size_t off = 20971520;
        for (int i = 0; i < 6; ++i) { wt[i] = (ushort*)(outf + off); off += 393216; }      // conv: 1536x512
        for (int i = 6; i < 12; ++i) { wt[i] = (ushort*)(outf + off); off += 131072; }     // proj: 512x512
    }

    hipMemsetAsync(zp, 0, 64, stream);

    // converts + weight transposes (every call; inputs re-pristined each time)
    convert_kernel<<<4096, 256, 0, stream>>>(x, xb);
    convert_kernel<<<4096, 256, 0, stream>>>(emb, eb);
    const dim3 tg3(48, 16), tg1(16, 16);
    transpose_kernel<<<tg3, 256, 0, stream>>>(dw1, wt[0], 1536);
    transpose_kernel<<<tg3, 256, 0, stream>>>(dw2, wt[1], 1536);
    transpose_kernel<<<tg3, 256, 0, stream>>>(pw1, wt[2], 1536);
    transpose_kernel<<<tg3, 256, 0, stream>>>(pw2, wt[3], 1536);
    transpose_kernel<<<tg3, 256, 0, stream>>>(ew1, wt[4], 1536);
    transpose_kernel<<<tg3, 256, 0, stream>>>(ew2, wt[5], 1536);
    transpose_kernel<<<tg1, 256, 0, stream>>>(ppw1, wt[6],  512);
    transpose_kernel<<<tg1, 256, 0, stream>>>(ppw2, wt[7],  512);
    transpose_kernel<<<tg1, 256, 0, stream>>>(epw1, wt[8],  512);
    transpose_kernel<<<tg1, 256, 0, stream>>>(epw2, wt[9],  512);
    transpose_kernel<<<tg1, 256, 0, stream>>>(spw1, wt[10], 512);
    transpose_kernel<<<tg1, 256, 0, stream>>>(spw2, wt[11], 512);

    idx_kernel<<<Mv / 256, 256, 0, stream>>>(pt, et, pbins, ebins, idxp, idxe);
    cumsum_kernel<<<Bv, Lv, 0, stream>>>(durt, cum, melint, outf + MEL_OFF);

    const dim3 ggrid(Fv / 128, Mv / 128);   // (4, 128)

    auto vpred = [&](const ushort* xin, const ushort* w1t, const float* b1, const float* g1,
                     const ushort* w2t, const float* b2, const float* g2,
                     const float* wl, const float* bl, float* pred) {
        gemm_bf16_kernel<3, 0><<<ggrid, 256, 0, stream>>>(xin, w1t, b1, bufC,
            nullptr, nullptr, nullptr, nullptr, nullptr, zp);
        rms_kernel<<<Mv, 128, 0, stream>>>(bufC, g1, bufD);
        gemm_bf16_kernel<3, 0><<<ggrid, 256, 0, stream>>>(bufD, w2t, b2, bufC,
            nullptr, nullptr, nullptr, nullptr, nullptr, zp);
        rms_kernel<<<Mv, 128, 0, stream>>>(bufC, g2, bufD);
        linear_kernel<<<Mv / 4, 256, 0, stream>>>(bufD, wl, bl, mask, pred);
    };

    // duration predictor on x
    vpred(xb, wt[0], db1, dg1, wt[1], db2, dg2, dwl, dbl, outf + DUR_OFF);

    // pitch: xin = x + proj(emb; pp)  -> xob (reused as vpred input buffer)
    gemm_bf16_kernel<1, 0><<<ggrid, 256, 0, stream>>>(eb, wt[6], ppb1, bufA,
        nullptr, nullptr, nullptr, nullptr, nullptr, zp);
    gemm_bf16_kernel<1, 1><<<ggrid, 256, 0, stream>>>(bufA, wt[7], ppb2, xob,
        x, nullptr, nullptr, nullptr, nullptr, zp);
    vpred(xob, wt[2], pb1, pg1, wt[3], pb2, pg2, pwl, pbl, outf + PIT_OFF);

    // energy: xin = x + proj(emb; ep)
    gemm_bf16_kernel<1, 0><<<ggrid, 256, 0, stream>>>(eb, wt[8], epb1, bufA,
        nullptr, nullptr, nullptr, nullptr, nullptr, zp);
    gemm_bf16_kernel<1, 1><<<ggrid, 256, 0, stream>>>(bufA, wt[9], epb2, xob,
        x, nullptr, nullptr, nullptr, nullptr, zp);
    vpred(xob, wt[4], eb1, eg1, wt[5], eb2, eg2, ewl, ebl, outf + ENG_OFF);

    // xo = x + pitch_emb[idxp] + energy_emb[idxe] + proj(emb; sp)  (fused epilogue)
    gemm_bf16_kernel<1, 0><<<ggrid, 256, 0, stream>>>(eb, wt[10], spb1, bufA,
        nullptr, nullptr, nullptr, nullptr, nullptr, zp);
    gemm_bf16_kernel<1, 2><<<ggrid, 256, 0, stream>>>(bufA, wt[11], spb2, xob,
        x, pemb, eemb, idxp, idxe, zp);

    // length regulate -> out (overwrites all d_out-front scratch)
    regulate_kernel<<<Bv * Tv, 128, 0, stream>>>(xob, cum, melint, outf + OUT_OFF);
}

// Round 3
// 844.856 us; speedup vs baseline: 3.7287x; 1.0847x over previous
//
#include <hip/hip_runtime.h>

// Problem constants
#define Bv    32
#define Lv    512
#define Hv    512
#define Fv    512
#define Tv    4096
#define Mv    (Bv*Lv)          // 16384 rows
#define NBINSv 256

// d_out layout (floats): out(B,T,H) | pit(B,L) | eng(B,L) | log_dur(B,L) | mel_len(B)
#define OUT_OFF 0
#define PIT_OFF (Bv*(size_t)Tv*Hv)              // 67108864
#define ENG_OFF (PIT_OFF + Mv)
#define DUR_OFF (ENG_OFF + Mv)
#define MEL_OFF (DUR_OFF + Mv)

typedef unsigned short ushort;
typedef __attribute__((ext_vector_type(8))) short   bf16x8;   // 8 bf16 in 4 VGPRs
typedef __attribute__((ext_vector_type(4))) float   f32x4;
typedef __attribute__((ext_vector_type(8))) unsigned short u16x8;

__device__ __forceinline__ float b2f(ushort u) {
    union { float f; unsigned u; } x; x.u = ((unsigned)u) << 16; return x.f;
}
__device__ __forceinline__ ushort f2b(float f) {
    union { float f; unsigned u; } x; x.f = f;
    unsigned r = x.u + 0x7fffu + ((x.u >> 16) & 1u);   // RNE
    return (ushort)(r >> 16);
}

#define GLL16(g, l) __builtin_amdgcn_global_load_lds( \
    (const __attribute__((address_space(1))) void*)(g), \
    (__attribute__((address_space(3))) void*)(l), 16, 0, 0)

// Struct-of-pointers kernel args for z-batched launches
template<int NZ> struct GArgs {
    const ushort* A[NZ];
    const ushort* W[NZ];
    const float*  bias[NZ];
    ushort*       C[NZ];
};
struct RmsArgs   { const ushort* h[3]; const float* g[3]; ushort* o[3]; };
struct RlArgs    { const ushort* h[3]; const float* g[3]; const float* wl[3]; const float* bl[3]; };
struct TransArgs { const float* src[6]; ushort* dst[6]; };
struct ConvArgs  { const float* src[2]; ushort* dst[2]; };

// ---------------------------------------------------------------------------
// bf16 MFMA GEMM, z-batched.  C[m,n] = epi( sum A*Wt + bias )
// Tile 128x128, BK=32, 256 thr = 4 waves, 4x4 16x16x32 MFMA tiles / wave.
// NTAPS=3 folds K=3 conv taps (zero pad via zero-page redirect).
// LDS XOR k-chunk swizzle -> 2-way conflicts (free).
// EPI: 0 relu; 1 relu+res; 2 relu+res+pe[idxp]+ee[idxe]
// ---------------------------------------------------------------------------
template<int NTAPS, int EPI, int NZ>
__global__ __launch_bounds__(256) void gemm_bf16_kernel(
    GArgs<NZ> ga, const float* __restrict__ res, const float* __restrict__ pe,
    const float* __restrict__ ee, const int* __restrict__ idxp,
    const int* __restrict__ idxe, const ushort* __restrict__ zp)
{
    constexpr int KTOT = NTAPS * 512;
    const int z = (NZ > 1) ? blockIdx.z : 0;
    const ushort* __restrict__ A    = ga.A[z];
    const ushort* __restrict__ Bt   = ga.W[z];
    const float*  __restrict__ bias = ga.bias[z];
    ushort*       __restrict__ C    = ga.C[z];

    __shared__ ushort As[128 * 32];
    __shared__ ushort Bs[128 * 32];

    const int tid = threadIdx.x;
    const int n0 = blockIdx.x * 128;
    const int m0 = blockIdx.y * 128;

    const int sar = tid >> 2;       // staging row
    const int sl  = tid & 3;        // staging 16B slot

    const int lane = tid & 63;
    const int w    = tid >> 6;
    const int wm   = (w & 1) * 64;
    const int wn   = (w >> 1) * 64;
    const int lr   = lane & 15;
    const int q    = lane >> 4;

    f32x4 acc[4][4];
    #pragma unroll
    for (int i = 0; i < 4; ++i)
        #pragma unroll
        for (int j = 0; j < 4; ++j) {
            f32x4 zz = {0.f, 0.f, 0.f, 0.f};
            acc[i][j] = zz;
        }

    for (int kt = 0; kt < NTAPS * 16; ++kt) {
        const int tap = (NTAPS == 3) ? (kt >> 4) : 0;
        const int kin = (NTAPS == 3) ? ((kt & 15) << 5) : (kt << 5);

        #pragma unroll
        for (int r = 0; r < 2; ++r) {
            const int row = sar + r * 64;
            const int m   = m0 + row;
            const int qg  = (sl - (row >> 1)) & 3;
            const ushort* asrc;
            if (NTAPS == 3) {
                const int l  = m & (Lv - 1);
                const int ls = l + tap - 1;
                asrc = ((unsigned)ls < (unsigned)Lv)
                     ? A + (size_t)(m + tap - 1) * 512 + kin + qg * 8
                     : zp;
            } else {
                asrc = A + (size_t)m * 512 + kin + qg * 8;
            }
            GLL16(asrc, &As[row * 32 + sl * 8]);
            const ushort* bsrc = Bt + (size_t)(n0 + row) * KTOT + tap * 512 + kin + qg * 8;
            GLL16(bsrc, &Bs[row * 32 + sl * 8]);
        }
        __syncthreads();

        bf16x8 af[4], bfr[4];
        #pragma unroll
        for (int i = 0; i < 4; ++i) {
            const int rm = wm + i * 16 + lr;
            af[i]  = *(const bf16x8*)&As[rm * 32 + (((q + (rm >> 1)) & 3) << 3)];
            const int rn = wn + i * 16 + lr;
            bfr[i] = *(const bf16x8*)&Bs[rn * 32 + (((q + (rn >> 1)) & 3) << 3)];
        }
        #pragma unroll
        for (int i = 0; i < 4; ++i)
            #pragma unroll
            for (int j = 0; j < 4; ++j)
                acc[i][j] = __builtin_amdgcn_mfma_f32_16x16x32_bf16(
                                af[i], bfr[j], acc[i][j], 0, 0, 0);
        __syncthreads();
    }

    // epilogue: C/D layout col = lane&15 (n), row = q*4 + reg
    #pragma unroll
    for (int i = 0; i < 4; ++i) {
        #pragma unroll
        for (int r = 0; r < 4; ++r) {
            const int m = m0 + wm + i * 16 + q * 4 + r;
            const size_t ro = (size_t)m * 512;
            int ip = 0, ie = 0;
            if (EPI == 2) { ip = idxp[m]; ie = idxe[m]; }
            #pragma unroll
            for (int j = 0; j < 4; ++j) {
                const int n = n0 + wn + j * 16 + lr;
                float v = acc[i][j][r] + bias[n];
                v = fmaxf(v, 0.f);
                if (EPI >= 1) v += res[ro + n];
                if (EPI == 2) v += pe[(size_t)ip * 512 + n] + ee[(size_t)ie * 512 + n];
                C[ro + n] = f2b(v);
            }
        }
    }
}

// ---------------------------------------------------------------------------
// fp32 -> bf16 convert, z-batched over {x, emb}
// ---------------------------------------------------------------------------
__global__ __launch_bounds__(256) void convert_kernel(ConvArgs ca)
{
    const float* __restrict__ X  = ca.src[blockIdx.y];
    ushort*      __restrict__ Xb = ca.dst[blockIdx.y];
    const size_t i = (size_t)blockIdx.x * 256 + threadIdx.x;
    const float4 a = ((const float4*)X)[2 * i];
    const float4 b = ((const float4*)X)[2 * i + 1];
    u16x8 o;
    o[0] = f2b(a.x); o[1] = f2b(a.y); o[2] = f2b(a.z); o[3] = f2b(a.w);
    o[4] = f2b(b.x); o[5] = f2b(b.y); o[6] = f2b(b.z); o[7] = f2b(b.w);
    *(u16x8*)(Xb + i * 8) = o;
}

// ---------------------------------------------------------------------------
// Weight transpose+convert, z-batched: W[kk][n] fp32 -> Wt[n][kk] bf16
// ---------------------------------------------------------------------------
__global__ __launch_bounds__(256) void transpose_kernel(TransArgs ta, int Ktot)
{
    const float* __restrict__ W  = ta.src[blockIdx.z];
    ushort*      __restrict__ Wt = ta.dst[blockIdx.z];
    __shared__ float t[32][33];
    const int k0 = blockIdx.x * 32, n0 = blockIdx.y * 32;
    const int r = threadIdx.x >> 5, c = threadIdx.x & 31;
    #pragma unroll
    for (int rr = 0; rr < 4; ++rr)
        t[r + rr * 8][c] = W[(size_t)(k0 + r + rr * 8) * 512 + n0 + c];
    __syncthreads();
    #pragma unroll
    for (int rr = 0; rr < 4; ++rr)
        Wt[(size_t)(n0 + r + rr * 8) * Ktot + k0 + c] = f2b(t[c][r + rr * 8]);
}

// ---------------------------------------------------------------------------
// RMSNorm, z-batched (grid.y = chain). bf16 in/out, fp32 math.
// ---------------------------------------------------------------------------
__global__ __launch_bounds__(128) void rms_kernel(RmsArgs ra)
{
    const int z = blockIdx.y;
    const int row = blockIdx.x;
    const int tid = threadIdx.x;
    const ushort* __restrict__ h = ra.h[z];
    const ushort4 hv = ((const ushort4*)(h + (size_t)row * 512))[tid];
    const float v0 = b2f(hv.x), v1 = b2f(hv.y), v2 = b2f(hv.z), v3 = b2f(hv.w);
    float ss = v0 * v0 + v1 * v1 + v2 * v2 + v3 * v3;
    #pragma unroll
    for (int off = 32; off; off >>= 1) ss += __shfl_down(ss, off, 64);
    __shared__ float p[2];
    if ((tid & 63) == 0) p[tid >> 6] = ss;
    __syncthreads();
    const float tot = p[0] + p[1];
    const float inv = 1.f / (sqrtf(tot * (1.f / 512.f)) + 1e-8f);
    const float4 gv = ((const float4*)ra.g[z])[tid];
    ushort4 ov;
    ov.x = f2b(gv.x * v0 * inv); ov.y = f2b(gv.y * v1 * inv);
    ov.z = f2b(gv.z * v2 * inv); ov.w = f2b(gv.w * v3 * inv);
    ((ushort4*)(ra.o[z] + (size_t)row * 512))[tid] = ov;
}

// ---------------------------------------------------------------------------
// Fused RMSNorm + linear head, z-batched. pred = mask ? 0 : inv*sum(g*h*wl)+bl
// 4 waves / block, one wave per row. Never materializes the normed tensor.
// pred layout: predbase + z*Mv + row  (z order = {pit, eng, dur} -> contiguous)
// ---------------------------------------------------------------------------
__global__ __launch_bounds__(256) void rmslin_kernel(
    RlArgs ra, const unsigned char* __restrict__ mask, float* __restrict__ predbase)
{
    const int z = blockIdx.y;
    const int wave = threadIdx.x >> 6, lane = threadIdx.x & 63;
    const int row = blockIdx.x * 4 + wave;
    const ushort* __restrict__ h = ra.h[z];
    const bf16x8 hv = *(const bf16x8*)(h + (size_t)row * 512 + lane * 8);
    const float4 g0 = *(const float4*)(ra.g[z] + lane * 8);
    const float4 g1 = *(const float4*)(ra.g[z] + lane * 8 + 4);
    const float4 w0 = *(const float4*)(ra.wl[z] + lane * 8);
    const float4 w1 = *(const float4*)(ra.wl[z] + lane * 8 + 4);
    float hf[8];
    #pragma unroll
    for (int t = 0; t < 8; ++t) hf[t] = b2f((ushort)hv[t]);
    float ss = 0.f, sgw = 0.f;
    #pragma unroll
    for (int t = 0; t < 8; ++t) ss += hf[t] * hf[t];
    sgw += hf[0]*g0.x*w0.x + hf[1]*g0.y*w0.y + hf[2]*g0.z*w0.z + hf[3]*g0.w*w0.w;
    sgw += hf[4]*g1.x*w1.x + hf[5]*g1.y*w1.y + hf[6]*g1.z*w1.z + hf[7]*g1.w*w1.w;
    #pragma unroll
    for (int off = 32; off; off >>= 1) {
        ss  += __shfl_down(ss,  off, 64);
        sgw += __shfl_down(sgw, off, 64);
    }
    if (lane == 0) {
        const float inv = 1.f / (sqrtf(ss * (1.f / 512.f)) + 1e-8f);
        predbase[(size_t)z * Mv + row] = mask[row] ? 0.f : (sgw * inv + ra.bl[z][0]);
    }
}

// ---------------------------------------------------------------------------
// searchsorted(bins, v, 'left') for pitch & energy targets
// ---------------------------------------------------------------------------
__global__ __launch_bounds__(256) void idx_kernel(
    const float* __restrict__ pt, const float* __restrict__ et,
    const float* __restrict__ pbins, const float* __restrict__ ebins,
    int* __restrict__ idxp, int* __restrict__ idxe)
{
    __shared__ float pb[NBINSv - 1], ebn[NBINSv - 1];
    const int tid = threadIdx.x;
    if (tid < NBINSv - 1) { pb[tid] = pbins[tid]; ebn[tid] = ebins[tid]; }
    __syncthreads();
    const int m = blockIdx.x * 256 + tid;
    const float pv = pt[m], ev = et[m];
    int lo = 0, hi = NBINSv - 1;
    while (lo < hi) { int mid = (lo + hi) >> 1; if (pb[mid] < pv) lo = mid + 1; else hi = mid; }
    idxp[m] = lo;
    lo = 0; hi = NBINSv - 1;
    while (lo < hi) { int mid = (lo + hi) >> 1; if (ebn[mid] < ev) lo = mid + 1; else hi = mid; }
    idxe[m] = lo;
}

// ---------------------------------------------------------------------------
// Per-batch inclusive cumsum of durations, plus mel_len
// ---------------------------------------------------------------------------
__global__ __launch_bounds__(512) void cumsum_kernel(
    const int* __restrict__ dur, int* __restrict__ cum,
    int* __restrict__ melint, float* __restrict__ melout)
{
    __shared__ int s[Lv];
    const int b = blockIdx.x, tid = threadIdx.x;
    s[tid] = dur[b * Lv + tid];
    __syncthreads();
    for (int off = 1; off < Lv; off <<= 1) {
        int t = (tid >= off) ? s[tid - off] : 0;
        __syncthreads();
        s[tid] += t;
        __syncthreads();
    }
    cum[b * Lv + tid] = s[tid];
    if (tid == Lv - 1) { melint[b] = s[tid]; melout[b] = (float)s[tid]; }
}

// ---------------------------------------------------------------------------
// Precompute regulate source map: tmap[b,t] = t < mel_len[b] ? src_row : -1
// ---------------------------------------------------------------------------
__global__ __launch_bounds__(256) void tmap_kernel(
    const int* __restrict__ cum, const int* __restrict__ melint,
    int* __restrict__ tmap)
{
    const int bt = blockIdx.x * 256 + threadIdx.x;
    const int b = bt >> 12;
    const int t = bt & (Tv - 1);
    const int* c = cum + b * Lv;
    int lo = 0, hi = Lv;
    while (lo < hi) { int mid = (lo + hi) >> 1; if (c[mid] <= t) lo = mid + 1; else hi = mid; }
    tmap[bt] = (t < melint[b]) ? (b * Lv + min(lo, Lv - 1)) : -1;
}

// ---------------------------------------------------------------------------
// Length regulate gather: out[bt,:] = tmap[bt] >= 0 ? xo[tmap[bt],:] : 0
// ---------------------------------------------------------------------------
__global__ __launch_bounds__(128) void regulate_kernel(
    const ushort* __restrict__ xo, const int* __restrict__ tmap,
    float* __restrict__ out)
{
    const int bt = blockIdx.x;
    const int src = tmap[bt];
    float4 v = make_float4(0.f, 0.f, 0.f, 0.f);
    if (src >= 0) {
        const ushort4 u = ((const ushort4*)(xo + (size_t)src * 512))[threadIdx.x];
        v.x = b2f(u.x); v.y = b2f(u.y); v.z = b2f(u.z); v.w = b2f(u.w);
    }
    ((float4*)(out + (size_t)bt * 512))[threadIdx.x] = v;
}

// ---------------------------------------------------------------------------
extern "C" void kernel_launch(void* const* d_in, const int* in_sizes, int n_in,
                              void* d_out, int out_size, void* d_ws, size_t ws_size,
                              hipStream_t stream)
{
    const float* x    = (const float*)d_in[0];
    const float* emb  = (const float*)d_in[1];
    const unsigned char* mask = (const unsigned char*)d_in[2];
    const int*   durt = (const int*)d_in[3];
    const float* pt   = (const float*)d_in[4];
    const float* et   = (const float*)d_in[5];
    const float* dw1 = (const float*)d_in[7],  *db1 = (const float*)d_in[8],
               * dg1 = (const float*)d_in[9],  *dw2 = (const float*)d_in[10],
               * db2 = (const float*)d_in[11], *dg2 = (const float*)d_in[12],
               * dwl = (const float*)d_in[13], *dbl = (const float*)d_in[14];
    const float* pw1 = (const float*)d_in[15], *pb1 = (const float*)d_in[16],
               * pg1 = (const float*)d_in[17], *pw2 = (const float*)d_in[18],
               * pb2 = (const float*)d_in[19], *pg2 = (const float*)d_in[20],
               * pwl = (const float*)d_in[21], *pbl = (const float*)d_in[22];
    const float* ew1 = (const float*)d_in[23], *eb1 = (const float*)d_in[24],
               * eg1 = (const float*)d_in[25], *ew2 = (const float*)d_in[26],
               * eb2 = (const float*)d_in[27], *eg2 = (const float*)d_in[28],
               * ewl = (const float*)d_in[29], *ebl = (const float*)d_in[30];
    const float* ppw1 = (const float*)d_in[31], *ppb1 = (const float*)d_in[32],
               * ppw2 = (const float*)d_in[33], *ppb2 = (const float*)d_in[34];
    const float* epw1 = (const float*)d_in[35], *epb1 = (const float*)d_in[36],
               * epw2 = (const float*)d_in[37], *epb2 = (const float*)d_in[38];
    const float* spw1 = (const float*)d_in[39], *spb1 = (const float*)d_in[40],
               * spw2 = (const float*)d_in[41], *spb2 = (const float*)d_in[42];
    const float* pbins = (const float*)d_in[43];
    const float* ebins = (const float*)d_in[44];
    const float* pemb  = (const float*)d_in[45];
    const float* eemb  = (const float*)d_in[46];

    float* outf = (float*)d_out;

    // ---- ws scratch (int offsets) ----
    int*    cum    = (int*)d_ws;                    // 16384
    int*    melint = cum + 16384;                   // 64
    int*    idxp   = melint + 64;                   // 16384
    int*    idxe   = idxp + 16384;                  // 16384
    ushort* zp     = (ushort*)(idxe + 16384);       // 32 ushorts (16B-aligned)
    int*    tmap   = idxe + 16448;                  // 131072
    ushort* xob    = (ushort*)((float*)d_ws + 262144);  // Mv*512 bf16, 1MB offset

    // ---- d_out front scratch (float offsets; regulate overwrites all) ----
    #define OBUF(i) ((ushort*)(outf + (size_t)(i) * 4194304))
    ushort* xb  = OBUF(0);   ushort* eb  = OBUF(1);
    ushort* pA0 = OBUF(2);   ushort* pA1 = OBUF(3);  ushort* pA2 = OBUF(4);
    ushort* xp  = OBUF(5);   ushort* xe  = OBUF(6);
    ushort* c0  = OBUF(7);   ushort* c1  = OBUF(8);  ushort* c2  = OBUF(9);
    ushort* r0  = OBUF(10);  ushort* r1  = OBUF(11); ushort* r2  = OBUF(12);
    ushort* wt[12];
    {
        size_t off = 13ull * 4194304;
        for (int i = 0; i < 6; ++i)  { wt[i] = (ushort*)(outf + off); off += 393216; }  // conv 1536x512
        for (int i = 6; i < 12; ++i) { wt[i] = (ushort*)(outf + off); off += 131072; }  // proj 512x512
    }

    hipMemsetAsync(zp, 0, 64, stream);

    // converts + transposes (batched)
    { ConvArgs ca = {{x, emb}, {xb, eb}};
      convert_kernel<<<dim3(4096, 2), 256, 0, stream>>>(ca); }
    { TransArgs ta = {{dw1, dw2, pw1, pw2, ew1, ew2}, {wt[0], wt[1], wt[2], wt[3], wt[4], wt[5]}};
      transpose_kernel<<<dim3(48, 16, 6), 256, 0, stream>>>(ta, 1536); }
    { TransArgs ta = {{ppw1, ppw2, epw1, epw2, spw1, spw2},
                      {wt[6], wt[7], wt[8], wt[9], wt[10], wt[11]}};
      transpose_kernel<<<dim3(16, 16, 6), 256, 0, stream>>>(ta, 512); }

    idx_kernel<<<Mv / 256, 256, 0, stream>>>(pt, et, pbins, ebins, idxp, idxe);
    cumsum_kernel<<<Bv, Lv, 0, stream>>>(durt, cum, melint, outf + MEL_OFF);
    tmap_kernel<<<Bv * Tv / 256, 256, 0, stream>>>(cum, melint, tmap);

    const dim3 g3(Fv / 128, Mv / 128, 3);
    const dim3 g2(Fv / 128, Mv / 128, 2);
    const dim3 g1(Fv / 128, Mv / 128, 1);

    // proj1: h = relu(emb @ w1 + b1) for pp/ep/sp
    { GArgs<3> a = {{eb, eb, eb}, {wt[6], wt[8], wt[10]}, {ppb1, epb1, spb1}, {pA0, pA1, pA2}};
      gemm_bf16_kernel<1, 0, 3><<<g3, 256, 0, stream>>>(a, nullptr, nullptr, nullptr,
                                                        nullptr, nullptr, zp); }
    // proj2 pp/ep: xin = x + relu(h @ w2 + b2)
    { GArgs<2> a = {{pA0, pA1}, {wt[7], wt[9]}, {ppb2, epb2}, {xp, xe}};
      gemm_bf16_kernel<1, 1, 2><<<g2, 256, 0, stream>>>(a, x, nullptr, nullptr,
                                                        nullptr, nullptr, zp); }
    // proj2 sp: xo = x + pe + ee + relu(h @ w2 + b2)
    { GArgs<1> a = {{pA2}, {wt[11]}, {spb2}, {xob}};
      gemm_bf16_kernel<1, 2, 1><<<g1, 256, 0, stream>>>(a, x, pemb, eemb, idxp, idxe, zp); }

    // conv1 for {pit, eng, dur}
    { GArgs<3> a = {{xp, xe, xb}, {wt[2], wt[4], wt[0]}, {pb1, eb1, db1}, {c0, c1, c2}};
      gemm_bf16_kernel<3, 0, 3><<<g3, 256, 0, stream>>>(a, nullptr, nullptr, nullptr,
                                                        nullptr, nullptr, zp); }
    { RmsArgs ra = {{c0, c1, c2}, {pg1, eg1, dg1}, {r0, r1, r2}};
      rms_kernel<<<dim3(Mv, 3), 128, 0, stream>>>(ra); }
    // conv2
    { GArgs<3> a = {{r0, r1, r2}, {wt[3], wt[5], wt[1]}, {pb2, eb2, db2}, {c0, c1, c2}};
      gemm_bf16_kernel<3, 0, 3><<<g3, 256, 0, stream>>>(a, nullptr, nullptr, nullptr,
                                                        nullptr, nullptr, zp); }
    // fused rms2 + linear head -> preds at PIT|ENG|DUR (contiguous, z-ordered)
    { RlArgs ra = {{c0, c1, c2}, {pg2, eg2, dg2}, {pwl, ewl, dwl}, {pbl, ebl, dbl}};
      rmslin_kernel<<<dim3(Mv / 4, 3), 256, 0, stream>>>(ra, mask, outf + PIT_OFF); }

    // length regulate gather -> out (overwrites all d_out-front scratch)
    regulate_kernel<<<Bv * Tv, 128, 0, stream>>>(xob, tmap, outf + OUT_OFF);
}